// Round 10
// baseline (3341.263 us; speedup 1.0000x reference)
//
#include <hip/hip_runtime.h>
#include <stdint.h>

typedef unsigned short u16;

#define T_STEPS 512
#define BATCH   64
#define DIN     512
#define HID     1024
#define G4      4096
#define THREADS 512
#define NBLK    64      // 64 col-blocks, each owns 16 units (64 gate-cols)
#define UPB     16
// block col c = u_local*4 + gate  <->  gcol = gate*1024 + nb*16 + u_local
// pre-transposed weight row p = (gcol & 1023)*4 + (gcol >> 10) = nb*64 + c

// ws map
#define XB_BYTES  ((size_t)T_STEPS * BATCH * DIN * 2)     // 32 MB bf16 x
#define WPR_OFF   XB_BYTES                                // wpr bf16 [4096][512] = 4 MB
#define WPR_BYTES ((size_t)4096 * 512 * 2)
#define UPR_OFF   (WPR_OFF + WPR_BYTES)                   // upr bf16 [4096][1024] = 8 MB
#define UPR_BYTES ((size_t)4096 * 1024 * 2)
#define H_OFF     (UPR_OFF + UPR_BYTES)                   // h: [ch 2][par 2][64KB]
#define H_BYTES   (4u * 65536)
#define F_OFF     (H_OFF + H_BYTES)                       // flags: [ch 2][64 x 16B]
#define F_BYTES   2048
#define WS_NEED   (F_OFF + F_BYTES)

typedef float f32x16 __attribute__((ext_vector_type(16)));
typedef short bf16x8 __attribute__((ext_vector_type(8)));
typedef unsigned uint32x4 __attribute__((ext_vector_type(4)));

__device__ __forceinline__ u16 f2bf(float f) {
  unsigned u = __float_as_uint(f);
  u += 0x7fffu + ((u >> 16) & 1u);   // RNE
  return (u16)(u >> 16);
}
__device__ __forceinline__ float sigm(float x) {
  return __builtin_amdgcn_rcpf(1.f + __expf(-x));
}
__device__ __forceinline__ float fast_tanh(float x) {
  return 1.f - 2.f * __builtin_amdgcn_rcpf(__expf(2.f * x) + 1.f);
}

// Coherent (L2-bypass, coherence-point) helpers; flat 64b VGPR address.
__device__ __forceinline__ uint32x4 load16_sc(uint64_t addr) {
  uint32x4 d;
  asm volatile("global_load_dwordx4 %0, %1, off sc0 sc1" : "=v"(d) : "v"(addr));
  return d;
}
__device__ __forceinline__ unsigned load4_sc(uint64_t addr) {
  unsigned d;
  asm volatile("global_load_dword %0, %1, off sc0 sc1" : "=v"(d) : "v"(addr));
  return d;
}
__device__ __forceinline__ void store16_sc(uint64_t addr, uint32x4 v) {
  asm volatile("global_store_dwordx4 %0, %1, off sc0 sc1" :: "v"(addr), "v"(v) : "memory");
}
__device__ __forceinline__ void store4_sc(uint64_t addr, unsigned v) {
  asm volatile("global_store_dword %0, %1, off sc0 sc1" :: "v"(addr), "v"(v) : "memory");
}
#define WAITV(n) asm volatile("s_waitcnt vmcnt(" #n ")" ::: "memory")

// x[B][T][D] fp32 -> xb[T][B][D] bf16
__global__ void cvt_x(const float* __restrict__ x, u16* __restrict__ xb) {
  int i = blockIdx.x * 256 + threadIdx.x;
  int dblk = i & 63;
  int rest = i >> 6;
  int b = rest & 63;
  int t = rest >> 6;
  const float4* s = reinterpret_cast<const float4*>(x + ((size_t)(b * T_STEPS + t)) * DIN + dblk * 8);
  float4 f0 = s[0], f1 = s[1];
  uint4 o;
  o.x = (unsigned)f2bf(f0.x) | ((unsigned)f2bf(f0.y) << 16);
  o.y = (unsigned)f2bf(f0.z) | ((unsigned)f2bf(f0.w) << 16);
  o.z = (unsigned)f2bf(f1.x) | ((unsigned)f2bf(f1.y) << 16);
  o.w = (unsigned)f2bf(f1.z) | ((unsigned)f2bf(f1.w) << 16);
  *reinterpret_cast<uint4*>(xb + ((size_t)(t * BATCH + b)) * DIN + dblk * 8) = o;
}

// src f32 [K][4096] -> dst bf16 [4096 p][K], p = (gcol&1023)*4 + (gcol>>10).
// grid = (K/64)*64 blocks of 256 threads; 64x64 tile via LDS transpose.
__global__ void prep_t(const float* __restrict__ src, u16* __restrict__ dst, int K) {
  __shared__ u16 tl[64][72];   // [j][k] padded
  const int kb = blockIdx.x >> 6, cb = blockIdx.x & 63;
  const int tid = threadIdx.x;
  {
    const int kl = tid >> 2, j0 = (tid & 3) * 16;
    const float* s = src + (size_t)(kb * 64 + kl) * 4096 + cb * 64 + j0;
#pragma unroll
    for (int c = 0; c < 16; c += 4) {
      float4 v = *(const float4*)(s + c);
      tl[j0 + c + 0][kl] = f2bf(v.x);
      tl[j0 + c + 1][kl] = f2bf(v.y);
      tl[j0 + c + 2][kl] = f2bf(v.z);
      tl[j0 + c + 3][kl] = f2bf(v.w);
    }
  }
  __syncthreads();
  {
    const int j = tid >> 2, kp = (tid & 3) * 16;
    const int gcol = cb * 64 + j;
    const int p = (gcol & 1023) * 4 + (gcol >> 10);
    const uint4* s = (const uint4*)&tl[j][kp];
    uint4* d = (uint4*)(dst + (size_t)p * K + kb * 64 + kp);
    d[0] = s[0];
    d[1] = s[1];
  }
}

// Dual-chain persistent LSTM. 64 blocks; block nb owns units [nb*16,nb*16+16)
// (64 gate-cols). Batch split into chain A (rows 0..31) / chain B (rows 32..63),
// processed alternately: chain Y's compute hides chain X's publish/poll RTs.
// 8 waves = 8 exclusive K-splits (128 HID + 64 DIN each) -> zero duplicate
// sc1 h-reads (64KB/block/chain-step). B-fragments live in registers from
// pre-transposed upr/wpr. 8-way K-partials reduced via LDS zp.
__launch_bounds__(THREADS, 2)
__global__ void lstm_kernel(const u16* __restrict__ upr, const u16* __restrict__ wpr,
                            const float* __restrict__ bias, const u16* __restrict__ xb,
                            char* __restrict__ ws, float* __restrict__ out) {
  __shared__ float zp[8][32][68];     // 69632 B
  __shared__ u16 hst[2][512];         // [ch][pb*16+pu]

  const int tid = threadIdx.x;
  const int nb  = blockIdx.x;
  const int l   = tid & 63;
  const int wv  = tid >> 6;          // = ks 0..7
  const int cl  = l & 31;
  const int q   = l >> 5;

  // ---- B fragments -> registers (coalesced b128 from pre-transposed bufs) ----
  bf16x8 ubf[2][8], wbf[2][4];
#pragma unroll
  for (int tile = 0; tile < 2; ++tile) {
    const u16* ub = upr + (size_t)(nb * 64 + tile * 32 + cl) * 1024 + wv * 128 + q * 8;
#pragma unroll
    for (int s = 0; s < 8; ++s) ubf[tile][s] = *(const bf16x8*)(ub + s * 16);
    const u16* wb = wpr + (size_t)(nb * 64 + tile * 32 + cl) * 512 + wv * 64 + q * 8;
#pragma unroll
    for (int s = 0; s < 4; ++s) wbf[tile][s] = *(const bf16x8*)(wb + s * 16);
  }

  // gate mapping: thread -> (row pb, unit pu)
  const int pb = tid & 31;
  const int pu = tid >> 5;           // 0..15
  const int j  = nb * UPB + pu;
  const float bi  = bias[j];
  const float bf_ = bias[1024 + j];
  const float bg  = bias[2048 + j];
  const float bo  = bias[3072 + j];
  float c0 = 0.f, c1 = 0.f;          // per-chain cell state (named, rule #20)

  const uint64_t hbase = (uint64_t)ws + H_OFF;
  const uint64_t fbase = (uint64_t)ws + F_OFF;
  // publish lane offset: lane l -> row l>>1, 16B-half l&1 of this block's slice
  const uint64_t puboff = (uint64_t)(nb >> 1) * 2048 + (uint64_t)(l >> 1) * 64 +
                          (uint64_t)(nb & 1) * 32 + (uint64_t)(l & 1) * 16;

  // pending-publish state (valid for phase >= 1; only wave 7 uses)
  uint32x4 pubv = {0, 0, 0, 0};
  uint64_t pubdst = 0, pubfl = 0;
  unsigned pubtag = 0;

  for (int phase = 0; phase < 2 * T_STEPS; ++phase) {
    const int ch = phase & 1;
    const int t  = phase >> 1;
    const uint64_t hb = hbase + (uint64_t)ch * 131072 + (uint64_t)(t & 1) * 65536;

    // ---- publish previous phase's h (store before poll; flag after ack) ----
    if (wv == 7 && phase) store16_sc(pubdst, pubv);

    // ---- x fragments (static; in flight across the poll) ----
    bf16x8 xf[4];
    {
      const u16* xr = xb + ((size_t)(t * 64 + ch * 32 + cl)) * 512 + wv * 64 + q * 8;
#pragma unroll
      for (int s = 0; s < 4; ++s) xf[s] = *(const bf16x8*)(xr + s * 16);
    }

    // ---- poll this wave's 8 producers (flags monotone; >= t) ----
    {
      const uint64_t fa = fbase + (uint64_t)ch * 1024 + (uint64_t)(wv * 8 + (l & 7)) * 16;
      while (true) {
        unsigned f = load4_sc(fa);
        WAITV(0);                       // also drains pub-store + xf loads
        if (__all(f >= (unsigned)t)) break;
        __builtin_amdgcn_s_sleep(1);
      }
    }
    if (wv == 7 && phase) store4_sc(pubfl, pubtag);

    // ---- h loads: 8 exclusive sc1 b128 per lane, all in flight ----
    uint32x4 hbuf[8];
#pragma unroll
    for (int s = 0; s < 8; ++s)
      hbuf[s] = load16_sc(hb + (uint64_t)((wv * 4 + (s >> 1)) * 2048) +
                          (uint64_t)cl * 64 + (uint64_t)((s & 1) * 32 + q * 16));

    // ---- MFMAs: x part first (data ready), h under counted vmcnt ----
    f32x16 acc0 = {0.f,0.f,0.f,0.f,0.f,0.f,0.f,0.f,0.f,0.f,0.f,0.f,0.f,0.f,0.f,0.f};
    f32x16 acc1 = {0.f,0.f,0.f,0.f,0.f,0.f,0.f,0.f,0.f,0.f,0.f,0.f,0.f,0.f,0.f,0.f};
#pragma unroll
    for (int s = 0; s < 4; ++s) {
      acc0 = __builtin_amdgcn_mfma_f32_32x32x16_bf16(xf[s], wbf[0][s], acc0, 0, 0, 0);
      acc1 = __builtin_amdgcn_mfma_f32_32x32x16_bf16(xf[s], wbf[1][s], acc1, 0, 0, 0);
    }
    WAITV(4); __builtin_amdgcn_sched_barrier(0);
#pragma unroll
    for (int s = 0; s < 4; ++s) {
      bf16x8 a = __builtin_bit_cast(bf16x8, hbuf[s]);
      acc0 = __builtin_amdgcn_mfma_f32_32x32x16_bf16(a, ubf[0][s], acc0, 0, 0, 0);
      acc1 = __builtin_amdgcn_mfma_f32_32x32x16_bf16(a, ubf[1][s], acc1, 0, 0, 0);
    }
    WAITV(0); __builtin_amdgcn_sched_barrier(0);
#pragma unroll
    for (int s = 4; s < 8; ++s) {
      bf16x8 a = __builtin_bit_cast(bf16x8, hbuf[s]);
      acc0 = __builtin_amdgcn_mfma_f32_32x32x16_bf16(a, ubf[0][s], acc0, 0, 0, 0);
      acc1 = __builtin_amdgcn_mfma_f32_32x32x16_bf16(a, ubf[1][s], acc1, 0, 0, 0);
    }

    // ---- K-partials -> LDS (C layout: col=cl, row=(r&3)+8*(r>>2)+4*q) ----
#pragma unroll
    for (int r = 0; r < 16; ++r) {
      int rl = (r & 3) + 8 * (r >> 2) + 4 * q;
      zp[wv][rl][cl]      = acc0[r];
      zp[wv][rl][32 + cl] = acc1[r];
    }
    __syncthreads();

    // ---- gates: thread (pb, pu); 8 partial-sets, 4 gates = one float4 ----
    float zi = bi, zf = bf_, zg = bg, zo = bo;
#pragma unroll
    for (int k2 = 0; k2 < 8; ++k2) {
      float4 v = *(const float4*)&zp[k2][pb][pu * 4];
      zi += v.x; zf += v.y; zg += v.z; zo += v.w;
    }
    float ig = sigm(zi), fg = sigm(zf), og = sigm(zo);
    float gg = fast_tanh(zg);
    float cr = ch ? c1 : c0;
    cr = fg * cr + ig * gg;
    float h = og * fast_tanh(cr);
    if (ch) c1 = cr; else c0 = cr;
    hst[ch][pb * 16 + pu] = f2bf(h);
    if (t == T_STEPS - 1) {
      float* orow = out + (size_t)(ch * 32 + pb) * 3072 + j;
      orow[0]    = h;       // h_T
      orow[1024] = h;       // h_T again
      orow[2048] = cr;      // c_T
    }
    __syncthreads();        // hst complete; zp reads done

    // ---- stage publish state for next phase (wave 7 issues it) ----
    pubv   = *(const uint32x4*)&hst[ch][l * 8];
    pubdst = hbase + (uint64_t)ch * 131072 + (uint64_t)((t + 1) & 1) * 65536 + puboff;
    pubfl  = fbase + (uint64_t)ch * 1024 + (uint64_t)nb * 16;
    pubtag = (unsigned)(t + 1);
  }
}

extern "C" void kernel_launch(void* const* d_in, const int* in_sizes, int n_in,
                              void* d_out, int out_size, void* d_ws, size_t ws_size,
                              hipStream_t stream) {
  const float* x = (const float*)d_in[0];
  const float* W = (const float*)d_in[1];
  const float* U = (const float*)d_in[2];
  const float* b = (const float*)d_in[3];
  float* out = (float*)d_out;

  if (ws_size < WS_NEED) return;  // loud failure: output stays poisoned

  u16* xb  = (u16*)d_ws;
  u16* wpr = (u16*)((char*)d_ws + WPR_OFF);
  u16* upr = (u16*)((char*)d_ws + UPR_OFF);

  // zero h buffers + flags — replayed every graph launch
  hipMemsetAsync((char*)d_ws + H_OFF, 0, H_BYTES + F_BYTES, stream);
  cvt_x<<<(T_STEPS * BATCH * DIN / 8 + 255) / 256, 256, 0, stream>>>(x, xb);
  prep_t<<<(512 / 64) * 64, 256, 0, stream>>>(W, wpr, 512);
  prep_t<<<(1024 / 64) * 64, 256, 0, stream>>>(U, upr, 1024);
  lstm_kernel<<<NBLK, THREADS, 0, stream>>>(upr, wpr, b, xb, (char*)d_ws, out);
}